// Round 5
// baseline (352.922 us; speedup 1.0000x reference)
//
#include <hip/hip_runtime.h>

#define NN 50000
#define NE 1600000
#define DIM 256
#define OUTD 64
#define ALPHA 0.2f

#define BSH 8                 // bucket = src >> 8 (256 nodes/bucket)
#define NB ((NN + 255) >> 8)  // 196 coarse buckets
#define P1 1000               // binning blocks
#define EPB (NE / P1)         // 1600 edges per block (exact)
#define TOT (NB * P1)         // 196000 (p,b) pairs
#define S1B ((TOT + 255) / 256)  // 766 scan blocks

#define RPW 16                // gemm rows per wave
#define RPB (4 * RPW)         // 64 rows per block
#define GEMM_BLOCKS ((NN + RPB - 1) / RPB)  // 782

typedef unsigned int u32;

// ---------------------------------------------------------------------------
// h = x @ W (fp32) + per-node logit partials s1 = h.a[:64], s2 = h.a[64:].
// Lane = output col o; wave register-blocks 16 rows so 4 LDS W-reads serve
// 64 FMAs (VALU-bound, not LDS-issue-bound). x rows are wave-uniform ->
// s_load_dwordx4 through the scalar path. Tail: clamp wave row base to NN-16
// (duplicate waves recompute identical values; benign identical stores).
// ---------------------------------------------------------------------------
__global__ __launch_bounds__(256) void gemm_h_kernel(
    const float* __restrict__ x, const float* __restrict__ W,
    const float* __restrict__ a, float* __restrict__ h,
    float* __restrict__ s1, float* __restrict__ s2)
{
  __shared__ float Wl[DIM][OUTD];  // 64 KB
  const int t = threadIdx.x;
  {
    const float4* Wv = (const float4*)W;
    float4* Wlv = (float4*)&Wl[0][0];
    for (int i = t; i < DIM * OUTD / 4; i += 256) Wlv[i] = Wv[i];
  }
  __syncthreads();

  const int o = t & 63;
  const int wv = __builtin_amdgcn_readfirstlane(t >> 6);
  int rb = blockIdx.x * RPB + wv * RPW;
  if (rb > NN - RPW) rb = NN - RPW;  // tail clamp (duplicates are benign)

  const float4* xb = (const float4*)(x + (size_t)rb * DIM);  // wave-uniform

  float acc[RPW];
#pragma unroll
  for (int j = 0; j < RPW; ++j) acc[j] = 0.f;

  for (int k4 = 0; k4 < DIM / 4; ++k4) {
    const float w0 = Wl[4 * k4 + 0][o];
    const float w1 = Wl[4 * k4 + 1][o];
    const float w2 = Wl[4 * k4 + 2][o];
    const float w3 = Wl[4 * k4 + 3][o];
#pragma unroll
    for (int j = 0; j < RPW; ++j) {
      const float4 u = xb[j * (DIM / 4) + k4];  // s_load_dwordx4
      acc[j] = fmaf(u.x, w0, acc[j]);
      acc[j] = fmaf(u.y, w1, acc[j]);
      acc[j] = fmaf(u.z, w2, acc[j]);
      acc[j] = fmaf(u.w, w3, acc[j]);
    }
  }

  const float a1 = a[o];
  const float a2 = a[OUTD + o];
#pragma unroll
  for (int j = 0; j < RPW; ++j) {
    const int r = rb + j;
    h[(size_t)r * OUTD + o] = acc[j];
    float p1 = acc[j] * a1;
    float p2 = acc[j] * a2;
    for (int off = 32; off > 0; off >>= 1) {
      p1 += __shfl_xor(p1, off);
      p2 += __shfl_xor(p2, off);
    }
    if (o == 0) { s1[r] = p1; s2[r] = p2; }
  }
}

// ---------------------------------------------------------------------------
// Per-block coarse histogram -> bcnt[p][b] (coalesced store, no global atomics)
// ---------------------------------------------------------------------------
__global__ __launch_bounds__(256) void hist_kernel(const int* __restrict__ src,
                                                   int* __restrict__ bcnt) {
  __shared__ int lh[NB];
  const int t = threadIdx.x;
  for (int i = t; i < NB; i += 256) lh[i] = 0;
  __syncthreads();
  const int base = blockIdx.x * EPB;
  for (int i = t; i < EPB; i += 256)
    atomicAdd(&lh[src[base + i] >> BSH], 1);
  __syncthreads();
  for (int i = t; i < NB; i += 256)
    bcnt[(size_t)blockIdx.x * NB + i] = lh[i];
}

// ---------------------------------------------------------------------------
// Scan of bcnt in b-major order (e = b*P1 + p), 3-kernel exclusive scan.
// binoff[e] = start of the private range for (block p, bucket b).
// ---------------------------------------------------------------------------
__global__ __launch_bounds__(256) void scan1_kernel(const int* __restrict__ bcnt,
                                                    int* __restrict__ binoff,
                                                    int* __restrict__ bsums) {
  __shared__ int tmp[256];
  const int t = threadIdx.x;
  const int e = blockIdx.x * 256 + t;
  int v = 0;
  if (e < TOT) {
    const int b = e / P1;
    const int p = e - b * P1;
    v = bcnt[(size_t)p * NB + b];
  }
  int x = v;
  tmp[t] = v;
  __syncthreads();
  for (int off = 1; off < 256; off <<= 1) {
    const int y = (t >= off) ? tmp[t - off] : 0;
    __syncthreads();
    x += y;
    tmp[t] = x;
    __syncthreads();
  }
  if (e < TOT) binoff[e] = x - v;
  if (t == 255) bsums[blockIdx.x] = x;
}

__global__ __launch_bounds__(1024) void scan2_kernel(int* __restrict__ bsums) {
  __shared__ int tmp[1024];
  const int t = threadIdx.x;
  const int v = (t < S1B) ? bsums[t] : 0;
  int x = v;
  tmp[t] = v;
  __syncthreads();
  for (int off = 1; off < 1024; off <<= 1) {
    const int y = (t >= off) ? tmp[t - off] : 0;
    __syncthreads();
    x += y;
    tmp[t] = x;
    __syncthreads();
  }
  if (t < S1B) bsums[t] = x - v;
}

__global__ __launch_bounds__(256) void scan3_kernel(int* __restrict__ binoff,
                                                    const int* __restrict__ bsums,
                                                    int* __restrict__ bstart) {
  const int e = blockIdx.x * 256 + threadIdx.x;
  if (e < TOT) {
    const int val = binoff[e] + bsums[blockIdx.x];
    binoff[e] = val;
    const int b = e / P1;
    if (e == b * P1) bstart[b] = val;  // p == 0
  }
  if (e == 0) bstart[NB] = NE;
}

// ---------------------------------------------------------------------------
// Binning: each block appends edges into its OWN private ranges of `binned`
// (one ds_add_rtn + one dense global write per edge; no global atomics).
// packed = (src&255)<<16 | dst  (dst < 65536).
// ---------------------------------------------------------------------------
__global__ __launch_bounds__(256) void bin_kernel(const int* __restrict__ src,
                                                  const int* __restrict__ dst,
                                                  const int* __restrict__ binoff,
                                                  u32* __restrict__ binned) {
  __shared__ int lcur[NB];
  const int t = threadIdx.x;
  for (int b = t; b < NB; b += 256)
    lcur[b] = binoff[(size_t)b * P1 + blockIdx.x];
  __syncthreads();
  const int base = blockIdx.x * EPB;
  for (int i = t; i < EPB; i += 256) {
    const int s = src[base + i];
    const u32 packed = ((u32)(s & 255) << 16) | (u32)dst[base + i];
    const int pos = atomicAdd(&lcur[s >> BSH], 1);
    binned[pos] = packed;
  }
}

// ---------------------------------------------------------------------------
// Per-bucket exact CSR: local histogram + scan -> rowstart/deg; scatter into
// the bucket's own dense region.
// ---------------------------------------------------------------------------
__global__ __launch_bounds__(256) void csr_kernel(const u32* __restrict__ binned,
                                                  const int* __restrict__ bstart,
                                                  int* __restrict__ rowstart,
                                                  int* __restrict__ deg,
                                                  int* __restrict__ edst) {
  __shared__ int cnt[256];
  __shared__ int off[256];
  const int b = blockIdx.x;
  const int beg = bstart[b], end = bstart[b + 1];
  const int t = threadIdx.x;
  cnt[t] = 0;
  __syncthreads();
  for (int i = beg + t; i < end; i += 256)
    atomicAdd(&cnt[binned[i] >> 16], 1);
  __syncthreads();
  const int v = cnt[t];
  int x = v;
  off[t] = v;
  __syncthreads();
  for (int o = 1; o < 256; o <<= 1) {
    const int y = (t >= o) ? off[t - o] : 0;
    __syncthreads();
    x += y;
    off[t] = x;
    __syncthreads();
  }
  off[t] = beg + x - v;
  const int node = (b << BSH) + t;
  if (node < NN) { rowstart[node] = beg + x - v; deg[node] = v; }
  __syncthreads();
  for (int i = beg + t; i < end; i += 256) {
    const u32 p = binned[i];
    const int slot = atomicAdd(&off[p >> 16], 1);
    edst[slot] = (int)(p & 0xFFFFu);
  }
}

// ---------------------------------------------------------------------------
// Aggregation: one wave per node.
// ---------------------------------------------------------------------------
__global__ __launch_bounds__(256) void agg_kernel(
    const float* __restrict__ h, const float* __restrict__ s1,
    const float* __restrict__ s2, const int* __restrict__ pre,
    const int* __restrict__ deg, const int* __restrict__ edst,
    float* __restrict__ out)
{
  const int lane = threadIdx.x & 63;
  const int node =
      __builtin_amdgcn_readfirstlane(blockIdx.x * 4 + (threadIdx.x >> 6));
  const int base = pre[node];
  const int cnt = deg[node];
  const float s1i = s1[node];

  float acc = 0.f;
  float wsum = 0.f;
  for (int c = 0; c < cnt; c += 64) {
    const int m = min(64, cnt - c);
    int d = 0;
    float w = 0.f;
    if (lane < m) {
      d = edst[base + c + lane];
      const float logit = s1i + s2[d];
      const float lr = logit > 0.f ? logit : ALPHA * logit;
      w = __expf(-lr);
    }
#pragma unroll 4
    for (int l = 0; l < m; ++l) {
      const int dv = __builtin_amdgcn_readlane(d, l);
      const float wv =
          __uint_as_float(__builtin_amdgcn_readlane(__float_as_uint(w), l));
      acc = fmaf(wv, h[(size_t)dv * OUTD + lane], acc);
      wsum += wv;
    }
  }
  const float val = (cnt > 0) ? (acc / wsum) : 0.f;
  const float r = val > 0.f ? val : (__expf(val) - 1.f);  // elu
  out[(size_t)node * OUTD + lane] = r;
}

// ---------------------------------------------------------------------------
extern "C" void kernel_launch(void* const* d_in, const int* in_sizes, int n_in,
                              void* d_out, int out_size, void* d_ws, size_t ws_size,
                              hipStream_t stream) {
  const float* x = (const float*)d_in[0];
  const int* ei = (const int*)d_in[1];
  const float* W = (const float*)d_in[2];
  const float* a = (const float*)d_in[3];
  float* out = (float*)d_out;

  // workspace layout (~28 MB)
  float* h = (float*)d_ws;              // NN*64
  float* s1 = h + (size_t)NN * OUTD;    // NN
  float* s2 = s1 + NN;                  // NN
  int* rowstart = (int*)(s2 + NN);      // NN
  int* deg = rowstart + NN;             // NN
  int* bcnt = deg + NN;                 // P1*NB
  int* binoff = bcnt + TOT;             // P1*NB
  int* bsums = binoff + TOT;            // S1B
  int* bstart = bsums + S1B;            // NB+1
  u32* binned = (u32*)(bstart + NB + 1);  // NE
  int* edst = (int*)(binned + NE);      // NE

  const int* src = ei;
  const int* dst = ei + NE;

  hipLaunchKernelGGL(gemm_h_kernel, dim3(GEMM_BLOCKS), dim3(256), 0, stream,
                     x, W, a, h, s1, s2);
  hipLaunchKernelGGL(hist_kernel, dim3(P1), dim3(256), 0, stream, src, bcnt);
  hipLaunchKernelGGL(scan1_kernel, dim3(S1B), dim3(256), 0, stream,
                     bcnt, binoff, bsums);
  hipLaunchKernelGGL(scan2_kernel, dim3(1), dim3(1024), 0, stream, bsums);
  hipLaunchKernelGGL(scan3_kernel, dim3(S1B), dim3(256), 0, stream,
                     binoff, bsums, bstart);
  hipLaunchKernelGGL(bin_kernel, dim3(P1), dim3(256), 0, stream,
                     src, dst, binoff, binned);
  hipLaunchKernelGGL(csr_kernel, dim3(NB), dim3(256), 0, stream,
                     binned, bstart, rowstart, deg, edst);
  hipLaunchKernelGGL(agg_kernel, dim3(NN / 4), dim3(256), 0, stream,
                     h, s1, s2, rowstart, deg, edst, out);
}

// Round 6
// 262.240 us; speedup vs baseline: 1.3458x; 1.3458x over previous
//
#include <hip/hip_runtime.h>

#define NN 50000
#define NE 1600000
#define DIM 256
#define OUTD 64
#define ALPHA 0.2f

#define BSH 8                 // bucket = src >> 8 (256 nodes/bucket)
#define NB ((NN + 255) >> 8)  // 196 coarse buckets
#define P1 1000               // binning blocks
#define EPB (NE / P1)         // 1600 edges per block (exact)
#define TOT (NB * P1)         // 196000 (p,b) pairs
#define S1B ((TOT + 255) / 256)  // 766 scan blocks

#define KC 64                 // gemm K-chunk
#define MT 64                 // gemm rows per block
#define XS_STRIDE 68          // KC + 4 pad (keeps 16B align; x-reads 2-way alias = free)
#define GEMM_BLOCKS ((NN + MT - 1) / MT)  // 782

typedef unsigned int u32;

// ---------------------------------------------------------------------------
// h = x @ W (fp32). Classic LDS-tiled GEMM: block = 64 rows x 64 cols,
// K chunked at 64. Per-thread 4x4 register tile; per k: 1 ds_read_b128 (W)
// + 4 broadcast ds_read_b32 (x) feed 16 FMAs. All global loads are per-lane
// coalesced float4 (1 KB/instr dense), unlike the previous wave-uniform
// loads that moved 16 useful bytes per transaction.
// ---------------------------------------------------------------------------
__global__ __launch_bounds__(256) void gemm_h_kernel(
    const float* __restrict__ x, const float* __restrict__ W,
    float* __restrict__ h)
{
  __shared__ float xs[MT][XS_STRIDE];  // 17.4 KB
  __shared__ float Wl[KC][OUTD];       // 16 KB
  const int t = threadIdx.x;
  const int tc = t & 15;   // col group: cols tc*4..tc*4+3
  const int tr = t >> 4;   // row group: rows tr*4..tr*4+3
  const int row0 = blockIdx.x * MT;

  // staging indices: thread loads row (t>>2), float4 segs (t&3)+{0,4,8,12}
  const int sr = t >> 2;
  const int ss = t & 3;
  int srg = row0 + sr;
  if (srg > NN - 1) srg = NN - 1;  // tail clamp (benign duplicate)
  const float4* xrow = (const float4*)(x + (size_t)srg * DIM);

  float acc[4][4] = {{0.f}};

  for (int kc = 0; kc < DIM; kc += KC) {
    // ---- stage x chunk: 64 rows x 64 k ----
#pragma unroll
    for (int i = 0; i < 4; ++i) {
      const float4 v = xrow[(kc >> 2) + ss + 4 * i];
      *(float4*)&xs[sr][(ss + 4 * i) * 4] = v;
    }
    // ---- stage W chunk: rows kc..kc+63 are 4096 contiguous floats ----
    {
      const float4* wsrc = (const float4*)(W + (size_t)kc * OUTD);
      float4* wdst = (float4*)&Wl[0][0];
#pragma unroll
      for (int i = 0; i < 4; ++i) wdst[t + 256 * i] = wsrc[t + 256 * i];
    }
    __syncthreads();

#pragma unroll 4
    for (int k = 0; k < KC; ++k) {
      const float4 wq = *(const float4*)&Wl[k][tc * 4];
      float xv[4];
#pragma unroll
      for (int j = 0; j < 4; ++j) xv[j] = xs[tr * 4 + j][k];
#pragma unroll
      for (int j = 0; j < 4; ++j) {
        acc[j][0] = fmaf(xv[j], wq.x, acc[j][0]);
        acc[j][1] = fmaf(xv[j], wq.y, acc[j][1]);
        acc[j][2] = fmaf(xv[j], wq.z, acc[j][2]);
        acc[j][3] = fmaf(xv[j], wq.w, acc[j][3]);
      }
    }
    __syncthreads();
  }

#pragma unroll
  for (int j = 0; j < 4; ++j) {
    const int r = row0 + tr * 4 + j;
    if (r < NN) {
      float4 v;
      v.x = acc[j][0]; v.y = acc[j][1]; v.z = acc[j][2]; v.w = acc[j][3];
      *(float4*)&h[(size_t)r * OUTD + tc * 4] = v;
    }
  }
}

// ---------------------------------------------------------------------------
// s1 = h . a[:64], s2 = h . a[64:] per node. One wave per row.
// ---------------------------------------------------------------------------
__global__ __launch_bounds__(256) void s1s2_kernel(
    const float* __restrict__ h, const float* __restrict__ a,
    float* __restrict__ s1, float* __restrict__ s2)
{
  const int lane = threadIdx.x & 63;
  const int r = blockIdx.x * 4 + (threadIdx.x >> 6);
  if (r >= NN) return;
  const float hv = h[(size_t)r * OUTD + lane];
  float p1 = hv * a[lane];
  float p2 = hv * a[OUTD + lane];
  for (int off = 32; off > 0; off >>= 1) {
    p1 += __shfl_xor(p1, off);
    p2 += __shfl_xor(p2, off);
  }
  if (lane == 0) { s1[r] = p1; s2[r] = p2; }
}

// ---------------------------------------------------------------------------
// Per-block coarse histogram -> bcnt[p][b] (coalesced store, no global atomics)
// ---------------------------------------------------------------------------
__global__ __launch_bounds__(256) void hist_kernel(const int* __restrict__ src,
                                                   int* __restrict__ bcnt) {
  __shared__ int lh[NB];
  const int t = threadIdx.x;
  for (int i = t; i < NB; i += 256) lh[i] = 0;
  __syncthreads();
  const int base = blockIdx.x * EPB;
  for (int i = t; i < EPB; i += 256)
    atomicAdd(&lh[src[base + i] >> BSH], 1);
  __syncthreads();
  for (int i = t; i < NB; i += 256)
    bcnt[(size_t)blockIdx.x * NB + i] = lh[i];
}

// ---------------------------------------------------------------------------
// Scan of bcnt in b-major order (e = b*P1 + p), 3-kernel exclusive scan.
// binoff[e] = start of the private range for (block p, bucket b).
// ---------------------------------------------------------------------------
__global__ __launch_bounds__(256) void scan1_kernel(const int* __restrict__ bcnt,
                                                    int* __restrict__ binoff,
                                                    int* __restrict__ bsums) {
  __shared__ int tmp[256];
  const int t = threadIdx.x;
  const int e = blockIdx.x * 256 + t;
  int v = 0;
  if (e < TOT) {
    const int b = e / P1;
    const int p = e - b * P1;
    v = bcnt[(size_t)p * NB + b];
  }
  int x = v;
  tmp[t] = v;
  __syncthreads();
  for (int off = 1; off < 256; off <<= 1) {
    const int y = (t >= off) ? tmp[t - off] : 0;
    __syncthreads();
    x += y;
    tmp[t] = x;
    __syncthreads();
  }
  if (e < TOT) binoff[e] = x - v;
  if (t == 255) bsums[blockIdx.x] = x;
}

__global__ __launch_bounds__(1024) void scan2_kernel(int* __restrict__ bsums) {
  __shared__ int tmp[1024];
  const int t = threadIdx.x;
  const int v = (t < S1B) ? bsums[t] : 0;
  int x = v;
  tmp[t] = v;
  __syncthreads();
  for (int off = 1; off < 1024; off <<= 1) {
    const int y = (t >= off) ? tmp[t - off] : 0;
    __syncthreads();
    x += y;
    tmp[t] = x;
    __syncthreads();
  }
  if (t < S1B) bsums[t] = x - v;
}

__global__ __launch_bounds__(256) void scan3_kernel(int* __restrict__ binoff,
                                                    const int* __restrict__ bsums,
                                                    int* __restrict__ bstart) {
  const int e = blockIdx.x * 256 + threadIdx.x;
  if (e < TOT) {
    const int val = binoff[e] + bsums[blockIdx.x];
    binoff[e] = val;
    const int b = e / P1;
    if (e == b * P1) bstart[b] = val;  // p == 0
  }
  if (e == 0) bstart[NB] = NE;
}

// ---------------------------------------------------------------------------
// Binning: each block appends edges into its OWN private ranges of `binned`
// (one ds_add_rtn + one dense global write per edge; no global atomics).
// packed = (src&255)<<16 | dst  (dst < 65536).
// ---------------------------------------------------------------------------
__global__ __launch_bounds__(256) void bin_kernel(const int* __restrict__ src,
                                                  const int* __restrict__ dst,
                                                  const int* __restrict__ binoff,
                                                  u32* __restrict__ binned) {
  __shared__ int lcur[NB];
  const int t = threadIdx.x;
  for (int b = t; b < NB; b += 256)
    lcur[b] = binoff[(size_t)b * P1 + blockIdx.x];
  __syncthreads();
  const int base = blockIdx.x * EPB;
  for (int i = t; i < EPB; i += 256) {
    const int s = src[base + i];
    const u32 packed = ((u32)(s & 255) << 16) | (u32)dst[base + i];
    const int pos = atomicAdd(&lcur[s >> BSH], 1);
    binned[pos] = packed;
  }
}

// ---------------------------------------------------------------------------
// Per-bucket exact CSR: local histogram + scan -> rowstart/deg; scatter into
// the bucket's own dense region.
// ---------------------------------------------------------------------------
__global__ __launch_bounds__(256) void csr_kernel(const u32* __restrict__ binned,
                                                  const int* __restrict__ bstart,
                                                  int* __restrict__ rowstart,
                                                  int* __restrict__ deg,
                                                  int* __restrict__ edst) {
  __shared__ int cnt[256];
  __shared__ int off[256];
  const int b = blockIdx.x;
  const int beg = bstart[b], end = bstart[b + 1];
  const int t = threadIdx.x;
  cnt[t] = 0;
  __syncthreads();
  for (int i = beg + t; i < end; i += 256)
    atomicAdd(&cnt[binned[i] >> 16], 1);
  __syncthreads();
  const int v = cnt[t];
  int x = v;
  off[t] = v;
  __syncthreads();
  for (int o = 1; o < 256; o <<= 1) {
    const int y = (t >= o) ? off[t - o] : 0;
    __syncthreads();
    x += y;
    off[t] = x;
    __syncthreads();
  }
  off[t] = beg + x - v;
  const int node = (b << BSH) + t;
  if (node < NN) { rowstart[node] = beg + x - v; deg[node] = v; }
  __syncthreads();
  for (int i = beg + t; i < end; i += 256) {
    const u32 p = binned[i];
    const int slot = atomicAdd(&off[p >> 16], 1);
    edst[slot] = (int)(p & 0xFFFFu);
  }
}

// ---------------------------------------------------------------------------
// Aggregation: one wave per node.
// ---------------------------------------------------------------------------
__global__ __launch_bounds__(256) void agg_kernel(
    const float* __restrict__ h, const float* __restrict__ s1,
    const float* __restrict__ s2, const int* __restrict__ pre,
    const int* __restrict__ deg, const int* __restrict__ edst,
    float* __restrict__ out)
{
  const int lane = threadIdx.x & 63;
  const int node =
      __builtin_amdgcn_readfirstlane(blockIdx.x * 4 + (threadIdx.x >> 6));
  const int base = pre[node];
  const int cnt = deg[node];
  const float s1i = s1[node];

  float acc = 0.f;
  float wsum = 0.f;
  for (int c = 0; c < cnt; c += 64) {
    const int m = min(64, cnt - c);
    int d = 0;
    float w = 0.f;
    if (lane < m) {
      d = edst[base + c + lane];
      const float logit = s1i + s2[d];
      const float lr = logit > 0.f ? logit : ALPHA * logit;
      w = __expf(-lr);
    }
#pragma unroll 4
    for (int l = 0; l < m; ++l) {
      const int dv = __builtin_amdgcn_readlane(d, l);
      const float wv =
          __uint_as_float(__builtin_amdgcn_readlane(__float_as_uint(w), l));
      acc = fmaf(wv, h[(size_t)dv * OUTD + lane], acc);
      wsum += wv;
    }
  }
  const float val = (cnt > 0) ? (acc / wsum) : 0.f;
  const float r = val > 0.f ? val : (__expf(val) - 1.f);  // elu
  out[(size_t)node * OUTD + lane] = r;
}

// ---------------------------------------------------------------------------
extern "C" void kernel_launch(void* const* d_in, const int* in_sizes, int n_in,
                              void* d_out, int out_size, void* d_ws, size_t ws_size,
                              hipStream_t stream) {
  const float* x = (const float*)d_in[0];
  const int* ei = (const int*)d_in[1];
  const float* W = (const float*)d_in[2];
  const float* a = (const float*)d_in[3];
  float* out = (float*)d_out;

  // workspace layout (~28 MB)
  float* h = (float*)d_ws;              // NN*64
  float* s1 = h + (size_t)NN * OUTD;    // NN
  float* s2 = s1 + NN;                  // NN
  int* rowstart = (int*)(s2 + NN);      // NN
  int* deg = rowstart + NN;             // NN
  int* bcnt = deg + NN;                 // P1*NB
  int* binoff = bcnt + TOT;             // P1*NB
  int* bsums = binoff + TOT;            // S1B
  int* bstart = bsums + S1B;            // NB+1
  u32* binned = (u32*)(bstart + NB + 1);  // NE
  int* edst = (int*)(binned + NE);      // NE

  const int* src = ei;
  const int* dst = ei + NE;

  hipLaunchKernelGGL(gemm_h_kernel, dim3(GEMM_BLOCKS), dim3(256), 0, stream,
                     x, W, h);
  hipLaunchKernelGGL(s1s2_kernel, dim3((NN + 3) / 4), dim3(256), 0, stream,
                     h, a, s1, s2);
  hipLaunchKernelGGL(hist_kernel, dim3(P1), dim3(256), 0, stream, src, bcnt);
  hipLaunchKernelGGL(scan1_kernel, dim3(S1B), dim3(256), 0, stream,
                     bcnt, binoff, bsums);
  hipLaunchKernelGGL(scan2_kernel, dim3(1), dim3(1024), 0, stream, bsums);
  hipLaunchKernelGGL(scan3_kernel, dim3(S1B), dim3(256), 0, stream,
                     binoff, bsums, bstart);
  hipLaunchKernelGGL(bin_kernel, dim3(P1), dim3(256), 0, stream,
                     src, dst, binoff, binned);
  hipLaunchKernelGGL(csr_kernel, dim3(NB), dim3(256), 0, stream,
                     binned, bstart, rowstart, deg, edst);
  hipLaunchKernelGGL(agg_kernel, dim3(NN / 4), dim3(256), 0, stream,
                     h, s1, s2, rowstart, deg, edst, out);
}

// Round 7
// 255.697 us; speedup vs baseline: 1.3802x; 1.0256x over previous
//
#include <hip/hip_runtime.h>

#define NN 50000
#define NE 1600000
#define DIM 256
#define OUTD 64
#define ALPHA 0.2f

#define BSH 8                 // bucket = src >> 8 (256 nodes/bucket)
#define NB ((NN + 255) >> 8)  // 196 coarse buckets
#define P1 1000               // binning blocks
#define EPB (NE / P1)         // 1600 edges per block (exact)
#define TOT (NB * P1)         // 196000 (p,b) pairs
#define S1B ((TOT + 255) / 256)  // 766 scan blocks

#define KC 64                 // gemm K-chunk
#define MT 64                 // gemm rows per block
#define XS_STRIDE 68          // KC + 4 pad
#define GEMM_BLOCKS ((NN + MT - 1) / MT)  // 782

typedef unsigned short u16;
typedef unsigned int u32;

__device__ __forceinline__ u16 f2bf(float f) {
  u32 b = __float_as_uint(f);
  b += 0x7FFFu + ((b >> 16) & 1u);  // RNE
  return (u16)(b >> 16);
}
__device__ __forceinline__ float bf2f(u16 v) {
  return __uint_as_float(((u32)v) << 16);
}

// ---------------------------------------------------------------------------
// h = x @ W (fp32 accum), stored as PACKED BF16 (halves gather bytes for agg).
// Epilogue also computes s1 = h.a[:64], s2 = h.a[64:] from the fp32 tile via
// 16-lane shuffle reduction (t = tr*16+tc; a row's 16 threads are contiguous
// lanes, so xor-offsets 8,4,2,1 stay in-group).
// ---------------------------------------------------------------------------
__global__ __launch_bounds__(256) void gemm_h_kernel(
    const float* __restrict__ x, const float* __restrict__ W,
    const float* __restrict__ a, u16* __restrict__ hb,
    float* __restrict__ s1, float* __restrict__ s2)
{
  __shared__ float xs[MT][XS_STRIDE];  // 17.4 KB
  __shared__ float Wl[KC][OUTD];       // 16 KB
  const int t = threadIdx.x;
  const int tc = t & 15;   // col group: cols tc*4..tc*4+3
  const int tr = t >> 4;   // row group: rows tr*4..tr*4+3
  const int row0 = blockIdx.x * MT;

  const int sr = t >> 2;
  const int ss = t & 3;
  int srg = row0 + sr;
  if (srg > NN - 1) srg = NN - 1;  // tail clamp (benign duplicate)
  const float4* xrow = (const float4*)(x + (size_t)srg * DIM);

  float acc[4][4] = {{0.f}};

  for (int kc = 0; kc < DIM; kc += KC) {
#pragma unroll
    for (int i = 0; i < 4; ++i) {
      const float4 v = xrow[(kc >> 2) + ss + 4 * i];
      *(float4*)&xs[sr][(ss + 4 * i) * 4] = v;
    }
    {
      const float4* wsrc = (const float4*)(W + (size_t)kc * OUTD);
      float4* wdst = (float4*)&Wl[0][0];
#pragma unroll
      for (int i = 0; i < 4; ++i) wdst[t + 256 * i] = wsrc[t + 256 * i];
    }
    __syncthreads();

#pragma unroll 4
    for (int k = 0; k < KC; ++k) {
      const float4 wq = *(const float4*)&Wl[k][tc * 4];
      float xv[4];
#pragma unroll
      for (int j = 0; j < 4; ++j) xv[j] = xs[tr * 4 + j][k];
#pragma unroll
      for (int j = 0; j < 4; ++j) {
        acc[j][0] = fmaf(xv[j], wq.x, acc[j][0]);
        acc[j][1] = fmaf(xv[j], wq.y, acc[j][1]);
        acc[j][2] = fmaf(xv[j], wq.z, acc[j][2]);
        acc[j][3] = fmaf(xv[j], wq.w, acc[j][3]);
      }
    }
    __syncthreads();
  }

  const float a0 = a[tc * 4 + 0], a1 = a[tc * 4 + 1];
  const float a2 = a[tc * 4 + 2], a3 = a[tc * 4 + 3];
  const float b0 = a[OUTD + tc * 4 + 0], b1 = a[OUTD + tc * 4 + 1];
  const float b2 = a[OUTD + tc * 4 + 2], b3 = a[OUTD + tc * 4 + 3];

#pragma unroll
  for (int j = 0; j < 4; ++j) {
    const int r = row0 + tr * 4 + j;
    float q1 = acc[j][0] * a0 + acc[j][1] * a1 + acc[j][2] * a2 + acc[j][3] * a3;
    float q2 = acc[j][0] * b0 + acc[j][1] * b1 + acc[j][2] * b2 + acc[j][3] * b3;
#pragma unroll
    for (int off = 8; off > 0; off >>= 1) {
      q1 += __shfl_xor(q1, off);
      q2 += __shfl_xor(q2, off);
    }
    if (r < NN) {
      uint2 p;
      p.x = (u32)f2bf(acc[j][0]) | ((u32)f2bf(acc[j][1]) << 16);
      p.y = (u32)f2bf(acc[j][2]) | ((u32)f2bf(acc[j][3]) << 16);
      *(uint2*)&hb[(size_t)r * OUTD + tc * 4] = p;
      if (tc == 0) { s1[r] = q1; s2[r] = q2; }
    }
  }
}

// ---------------------------------------------------------------------------
// Per-block coarse histogram -> bcnt[p][b] (coalesced store, no global atomics)
// ---------------------------------------------------------------------------
__global__ __launch_bounds__(256) void hist_kernel(const int* __restrict__ src,
                                                   int* __restrict__ bcnt) {
  __shared__ int lh[NB];
  const int t = threadIdx.x;
  for (int i = t; i < NB; i += 256) lh[i] = 0;
  __syncthreads();
  const int base = blockIdx.x * EPB;
  for (int i = t; i < EPB; i += 256)
    atomicAdd(&lh[src[base + i] >> BSH], 1);
  __syncthreads();
  for (int i = t; i < NB; i += 256)
    bcnt[(size_t)blockIdx.x * NB + i] = lh[i];
}

// ---------------------------------------------------------------------------
// Scan of bcnt in b-major order (e = b*P1 + p), 3-kernel exclusive scan.
// ---------------------------------------------------------------------------
__global__ __launch_bounds__(256) void scan1_kernel(const int* __restrict__ bcnt,
                                                    int* __restrict__ binoff,
                                                    int* __restrict__ bsums) {
  __shared__ int tmp[256];
  const int t = threadIdx.x;
  const int e = blockIdx.x * 256 + t;
  int v = 0;
  if (e < TOT) {
    const int b = e / P1;
    const int p = e - b * P1;
    v = bcnt[(size_t)p * NB + b];
  }
  int x = v;
  tmp[t] = v;
  __syncthreads();
  for (int off = 1; off < 256; off <<= 1) {
    const int y = (t >= off) ? tmp[t - off] : 0;
    __syncthreads();
    x += y;
    tmp[t] = x;
    __syncthreads();
  }
  if (e < TOT) binoff[e] = x - v;
  if (t == 255) bsums[blockIdx.x] = x;
}

__global__ __launch_bounds__(1024) void scan2_kernel(int* __restrict__ bsums) {
  __shared__ int tmp[1024];
  const int t = threadIdx.x;
  const int v = (t < S1B) ? bsums[t] : 0;
  int x = v;
  tmp[t] = v;
  __syncthreads();
  for (int off = 1; off < 1024; off <<= 1) {
    const int y = (t >= off) ? tmp[t - off] : 0;
    __syncthreads();
    x += y;
    tmp[t] = x;
    __syncthreads();
  }
  if (t < S1B) bsums[t] = x - v;
}

__global__ __launch_bounds__(256) void scan3_kernel(int* __restrict__ binoff,
                                                    const int* __restrict__ bsums,
                                                    int* __restrict__ bstart) {
  const int e = blockIdx.x * 256 + threadIdx.x;
  if (e < TOT) {
    const int val = binoff[e] + bsums[blockIdx.x];
    binoff[e] = val;
    const int b = e / P1;
    if (e == b * P1) bstart[b] = val;  // p == 0
  }
  if (e == 0) bstart[NB] = NE;
}

// ---------------------------------------------------------------------------
// Binning: block-private ranges, one ds_add_rtn + one dense global write/edge.
// packed = (src&255)<<16 | dst  (dst < 65536).
// ---------------------------------------------------------------------------
__global__ __launch_bounds__(256) void bin_kernel(const int* __restrict__ src,
                                                  const int* __restrict__ dst,
                                                  const int* __restrict__ binoff,
                                                  u32* __restrict__ binned) {
  __shared__ int lcur[NB];
  const int t = threadIdx.x;
  for (int b = t; b < NB; b += 256)
    lcur[b] = binoff[(size_t)b * P1 + blockIdx.x];
  __syncthreads();
  const int base = blockIdx.x * EPB;
  for (int i = t; i < EPB; i += 256) {
    const int s = src[base + i];
    const u32 packed = ((u32)(s & 255) << 16) | (u32)dst[base + i];
    const int pos = atomicAdd(&lcur[s >> BSH], 1);
    binned[pos] = packed;
  }
}

// ---------------------------------------------------------------------------
// Per-bucket exact CSR: local histogram + scan -> rowstart/deg; dense scatter.
// ---------------------------------------------------------------------------
__global__ __launch_bounds__(256) void csr_kernel(const u32* __restrict__ binned,
                                                  const int* __restrict__ bstart,
                                                  int* __restrict__ rowstart,
                                                  int* __restrict__ deg,
                                                  int* __restrict__ edst) {
  __shared__ int cnt[256];
  __shared__ int off[256];
  const int b = blockIdx.x;
  const int beg = bstart[b], end = bstart[b + 1];
  const int t = threadIdx.x;
  cnt[t] = 0;
  __syncthreads();
  for (int i = beg + t; i < end; i += 256)
    atomicAdd(&cnt[binned[i] >> 16], 1);
  __syncthreads();
  const int v = cnt[t];
  int x = v;
  off[t] = v;
  __syncthreads();
  for (int o = 1; o < 256; o <<= 1) {
    const int y = (t >= o) ? off[t - o] : 0;
    __syncthreads();
    x += y;
    off[t] = x;
    __syncthreads();
  }
  off[t] = beg + x - v;
  const int node = (b << BSH) + t;
  if (node < NN) { rowstart[node] = beg + x - v; deg[node] = v; }
  __syncthreads();
  for (int i = beg + t; i < end; i += 256) {
    const u32 p = binned[i];
    const int slot = atomicAdd(&off[p >> 16], 1);
    edst[slot] = (int)(p & 0xFFFFu);
  }
}

// ---------------------------------------------------------------------------
// Aggregation: one wave per node; h gathered as bf16 (2 B/lane = 128 B/edge).
// ---------------------------------------------------------------------------
__global__ __launch_bounds__(256) void agg_kernel(
    const u16* __restrict__ hb, const float* __restrict__ s1,
    const float* __restrict__ s2, const int* __restrict__ pre,
    const int* __restrict__ deg, const int* __restrict__ edst,
    float* __restrict__ out)
{
  const int lane = threadIdx.x & 63;
  const int node =
      __builtin_amdgcn_readfirstlane(blockIdx.x * 4 + (threadIdx.x >> 6));
  const int base = pre[node];
  const int cnt = deg[node];
  const float s1i = s1[node];

  float acc = 0.f;
  float wsum = 0.f;
  for (int c = 0; c < cnt; c += 64) {
    const int m = min(64, cnt - c);
    int d = 0;
    float w = 0.f;
    if (lane < m) {
      d = edst[base + c + lane];
      const float logit = s1i + s2[d];
      const float lr = logit > 0.f ? logit : ALPHA * logit;
      w = __expf(-lr);
    }
#pragma unroll 4
    for (int l = 0; l < m; ++l) {
      const int dv = __builtin_amdgcn_readlane(d, l);
      const float wv =
          __uint_as_float(__builtin_amdgcn_readlane(__float_as_uint(w), l));
      acc = fmaf(wv, bf2f(hb[(size_t)dv * OUTD + lane]), acc);
      wsum += wv;
    }
  }
  const float val = (cnt > 0) ? (acc / wsum) : 0.f;
  const float r = val > 0.f ? val : (__expf(val) - 1.f);  // elu
  out[(size_t)node * OUTD + lane] = r;
}

// ---------------------------------------------------------------------------
extern "C" void kernel_launch(void* const* d_in, const int* in_sizes, int n_in,
                              void* d_out, int out_size, void* d_ws, size_t ws_size,
                              hipStream_t stream) {
  const float* x = (const float*)d_in[0];
  const int* ei = (const int*)d_in[1];
  const float* W = (const float*)d_in[2];
  const float* a = (const float*)d_in[3];
  float* out = (float*)d_out;

  // workspace layout (~22 MB)
  u16* hb = (u16*)d_ws;                   // NN*64 bf16 (6.4 MB)
  float* s1 = (float*)(hb + (size_t)NN * OUTD);  // NN
  float* s2 = s1 + NN;                    // NN
  int* rowstart = (int*)(s2 + NN);        // NN
  int* deg = rowstart + NN;               // NN
  int* bcnt = deg + NN;                   // P1*NB
  int* binoff = bcnt + TOT;               // P1*NB
  int* bsums = binoff + TOT;              // S1B
  int* bstart = bsums + S1B;              // NB+1
  u32* binned = (u32*)(bstart + NB + 1);  // NE
  int* edst = (int*)(binned + NE);        // NE

  const int* src = ei;
  const int* dst = ei + NE;

  hipLaunchKernelGGL(gemm_h_kernel, dim3(GEMM_BLOCKS), dim3(256), 0, stream,
                     x, W, a, hb, s1, s2);
  hipLaunchKernelGGL(hist_kernel, dim3(P1), dim3(256), 0, stream, src, bcnt);
  hipLaunchKernelGGL(scan1_kernel, dim3(S1B), dim3(256), 0, stream,
                     bcnt, binoff, bsums);
  hipLaunchKernelGGL(scan2_kernel, dim3(1), dim3(1024), 0, stream, bsums);
  hipLaunchKernelGGL(scan3_kernel, dim3(S1B), dim3(256), 0, stream,
                     binoff, bsums, bstart);
  hipLaunchKernelGGL(bin_kernel, dim3(P1), dim3(256), 0, stream,
                     src, dst, binoff, binned);
  hipLaunchKernelGGL(csr_kernel, dim3(NB), dim3(256), 0, stream,
                     binned, bstart, rowstart, deg, edst);
  hipLaunchKernelGGL(agg_kernel, dim3(NN / 4), dim3(256), 0, stream,
                     hb, s1, s2, rowstart, deg, edst, out);
}

// Round 8
// 210.533 us; speedup vs baseline: 1.6763x; 1.2145x over previous
//
#include <hip/hip_runtime.h>

#define NN 50000
#define NE 1600000
#define DIM 256
#define OUTD 64
#define ALPHA 0.2f

#define BSH 8                 // bucket = src >> 8 (256 nodes/bucket)
#define NB ((NN + 255) >> 8)  // 196 coarse buckets
#define P1 1000               // binning blocks
#define EPB (NE / P1)         // 1600 edges per block (exact)
#define TOT (NB * P1)         // 196000 (p,b) pairs
#define S1B ((TOT + 255) / 256)  // 766 scan blocks

#define KC 64                 // gemm K-chunk
#define MT 64                 // gemm rows per block
#define XS_STRIDE 68          // KC + 4 pad
#define GEMM_BLOCKS ((NN + MT - 1) / MT)  // 782

typedef unsigned short u16;
typedef unsigned int u32;

__device__ __forceinline__ u16 f2bf(float f) {
  u32 b = __float_as_uint(f);
  b += 0x7FFFu + ((b >> 16) & 1u);  // RNE
  return (u16)(b >> 16);
}
__device__ __forceinline__ float bflo(u32 u) { return __uint_as_float(u << 16); }
__device__ __forceinline__ float bfhi(u32 u) { return __uint_as_float(u & 0xFFFF0000u); }

// ---------------------------------------------------------------------------
// h = x @ W (fp32 accum), stored PACKED BF16; epilogue computes s1/s2 via
// 16-lane shuffle reduction.
// ---------------------------------------------------------------------------
__global__ __launch_bounds__(256) void gemm_h_kernel(
    const float* __restrict__ x, const float* __restrict__ W,
    const float* __restrict__ a, u16* __restrict__ hb,
    float* __restrict__ s1, float* __restrict__ s2)
{
  __shared__ float xs[MT][XS_STRIDE];  // 17.4 KB
  __shared__ float Wl[KC][OUTD];       // 16 KB
  const int t = threadIdx.x;
  const int tc = t & 15;
  const int tr = t >> 4;
  const int row0 = blockIdx.x * MT;

  const int sr = t >> 2;
  const int ss = t & 3;
  int srg = row0 + sr;
  if (srg > NN - 1) srg = NN - 1;  // tail clamp (benign duplicate)
  const float4* xrow = (const float4*)(x + (size_t)srg * DIM);

  float acc[4][4] = {{0.f}};

  for (int kc = 0; kc < DIM; kc += KC) {
#pragma unroll
    for (int i = 0; i < 4; ++i) {
      const float4 v = xrow[(kc >> 2) + ss + 4 * i];
      *(float4*)&xs[sr][(ss + 4 * i) * 4] = v;
    }
    {
      const float4* wsrc = (const float4*)(W + (size_t)kc * OUTD);
      float4* wdst = (float4*)&Wl[0][0];
#pragma unroll
      for (int i = 0; i < 4; ++i) wdst[t + 256 * i] = wsrc[t + 256 * i];
    }
    __syncthreads();

#pragma unroll 4
    for (int k = 0; k < KC; ++k) {
      const float4 wq = *(const float4*)&Wl[k][tc * 4];
      float xv[4];
#pragma unroll
      for (int j = 0; j < 4; ++j) xv[j] = xs[tr * 4 + j][k];
#pragma unroll
      for (int j = 0; j < 4; ++j) {
        acc[j][0] = fmaf(xv[j], wq.x, acc[j][0]);
        acc[j][1] = fmaf(xv[j], wq.y, acc[j][1]);
        acc[j][2] = fmaf(xv[j], wq.z, acc[j][2]);
        acc[j][3] = fmaf(xv[j], wq.w, acc[j][3]);
      }
    }
    __syncthreads();
  }

  const float a0 = a[tc * 4 + 0], a1 = a[tc * 4 + 1];
  const float a2 = a[tc * 4 + 2], a3 = a[tc * 4 + 3];
  const float b0 = a[OUTD + tc * 4 + 0], b1 = a[OUTD + tc * 4 + 1];
  const float b2 = a[OUTD + tc * 4 + 2], b3 = a[OUTD + tc * 4 + 3];

#pragma unroll
  for (int j = 0; j < 4; ++j) {
    const int r = row0 + tr * 4 + j;
    float q1 = acc[j][0] * a0 + acc[j][1] * a1 + acc[j][2] * a2 + acc[j][3] * a3;
    float q2 = acc[j][0] * b0 + acc[j][1] * b1 + acc[j][2] * b2 + acc[j][3] * b3;
#pragma unroll
    for (int off = 8; off > 0; off >>= 1) {
      q1 += __shfl_xor(q1, off);
      q2 += __shfl_xor(q2, off);
    }
    if (r < NN) {
      uint2 p;
      p.x = (u32)f2bf(acc[j][0]) | ((u32)f2bf(acc[j][1]) << 16);
      p.y = (u32)f2bf(acc[j][2]) | ((u32)f2bf(acc[j][3]) << 16);
      *(uint2*)&hb[(size_t)r * OUTD + tc * 4] = p;
      if (tc == 0) { s1[r] = q1; s2[r] = q2; }
    }
  }
}

// ---------------------------------------------------------------------------
__global__ __launch_bounds__(256) void hist_kernel(const int* __restrict__ src,
                                                   int* __restrict__ bcnt) {
  __shared__ int lh[NB];
  const int t = threadIdx.x;
  for (int i = t; i < NB; i += 256) lh[i] = 0;
  __syncthreads();
  const int base = blockIdx.x * EPB;
  for (int i = t; i < EPB; i += 256)
    atomicAdd(&lh[src[base + i] >> BSH], 1);
  __syncthreads();
  for (int i = t; i < NB; i += 256)
    bcnt[(size_t)blockIdx.x * NB + i] = lh[i];
}

// ---------------------------------------------------------------------------
__global__ __launch_bounds__(256) void scan1_kernel(const int* __restrict__ bcnt,
                                                    int* __restrict__ binoff,
                                                    int* __restrict__ bsums) {
  __shared__ int tmp[256];
  const int t = threadIdx.x;
  const int e = blockIdx.x * 256 + t;
  int v = 0;
  if (e < TOT) {
    const int b = e / P1;
    const int p = e - b * P1;
    v = bcnt[(size_t)p * NB + b];
  }
  int x = v;
  tmp[t] = v;
  __syncthreads();
  for (int off = 1; off < 256; off <<= 1) {
    const int y = (t >= off) ? tmp[t - off] : 0;
    __syncthreads();
    x += y;
    tmp[t] = x;
    __syncthreads();
  }
  if (e < TOT) binoff[e] = x - v;
  if (t == 255) bsums[blockIdx.x] = x;
}

__global__ __launch_bounds__(1024) void scan2_kernel(int* __restrict__ bsums) {
  __shared__ int tmp[1024];
  const int t = threadIdx.x;
  const int v = (t < S1B) ? bsums[t] : 0;
  int x = v;
  tmp[t] = v;
  __syncthreads();
  for (int off = 1; off < 1024; off <<= 1) {
    const int y = (t >= off) ? tmp[t - off] : 0;
    __syncthreads();
    x += y;
    tmp[t] = x;
    __syncthreads();
  }
  if (t < S1B) bsums[t] = x - v;
}

__global__ __launch_bounds__(256) void scan3_kernel(int* __restrict__ binoff,
                                                    const int* __restrict__ bsums,
                                                    int* __restrict__ bstart) {
  const int e = blockIdx.x * 256 + threadIdx.x;
  if (e < TOT) {
    const int val = binoff[e] + bsums[blockIdx.x];
    binoff[e] = val;
    const int b = e / P1;
    if (e == b * P1) bstart[b] = val;  // p == 0
  }
  if (e == 0) bstart[NB] = NE;
}

// ---------------------------------------------------------------------------
__global__ __launch_bounds__(256) void bin_kernel(const int* __restrict__ src,
                                                  const int* __restrict__ dst,
                                                  const int* __restrict__ binoff,
                                                  u32* __restrict__ binned) {
  __shared__ int lcur[NB];
  const int t = threadIdx.x;
  for (int b = t; b < NB; b += 256)
    lcur[b] = binoff[(size_t)b * P1 + blockIdx.x];
  __syncthreads();
  const int base = blockIdx.x * EPB;
  for (int i = t; i < EPB; i += 256) {
    const int s = src[base + i];
    const u32 packed = ((u32)(s & 255) << 16) | (u32)dst[base + i];
    const int pos = atomicAdd(&lcur[s >> BSH], 1);
    binned[pos] = packed;
  }
}

// ---------------------------------------------------------------------------
__global__ __launch_bounds__(256) void csr_kernel(const u32* __restrict__ binned,
                                                  const int* __restrict__ bstart,
                                                  int* __restrict__ rowstart,
                                                  int* __restrict__ deg,
                                                  int* __restrict__ edst) {
  __shared__ int cnt[256];
  __shared__ int off[256];
  const int b = blockIdx.x;
  const int beg = bstart[b], end = bstart[b + 1];
  const int t = threadIdx.x;
  cnt[t] = 0;
  __syncthreads();
  for (int i = beg + t; i < end; i += 256)
    atomicAdd(&cnt[binned[i] >> 16], 1);
  __syncthreads();
  const int v = cnt[t];
  int x = v;
  off[t] = v;
  __syncthreads();
  for (int o = 1; o < 256; o <<= 1) {
    const int y = (t >= o) ? off[t - o] : 0;
    __syncthreads();
    x += y;
    off[t] = x;
    __syncthreads();
  }
  off[t] = beg + x - v;
  const int node = (b << BSH) + t;
  if (node < NN) { rowstart[node] = beg + x - v; deg[node] = v; }
  __syncthreads();
  for (int i = beg + t; i < end; i += 256) {
    const u32 p = binned[i];
    const int slot = atomicAdd(&off[p >> 16], 1);
    edst[slot] = (int)(p & 0xFFFFu);
  }
}

// ---------------------------------------------------------------------------
// Aggregation: one wave per node; 4 edges per inner iteration.
// lane = (g = lane>>4 edge-group, seg = lane&15 dim-segment). Group g handles
// edge c+e+g; each lane loads uint2 = 4 bf16 dims of that edge's h-row -> one
// gather instr covers 4 rows (512 B useful). (d,w) come via per-lane-dynamic
// __shfl (ds_bpermute). Tail lanes see w=0 (branch-free). Epilogue: xor-16/32
// cross-group reduce; 16 lanes store float4.
// ---------------------------------------------------------------------------
__global__ __launch_bounds__(256) void agg_kernel(
    const u16* __restrict__ hb, const float* __restrict__ s1,
    const float* __restrict__ s2, const int* __restrict__ pre,
    const int* __restrict__ deg, const int* __restrict__ edst,
    float* __restrict__ out)
{
  const int lane = threadIdx.x & 63;
  const int g = lane >> 4;
  const int seg = lane & 15;
  const int node =
      __builtin_amdgcn_readfirstlane(blockIdx.x * 4 + (threadIdx.x >> 6));
  const int base = pre[node];
  const int cnt = deg[node];
  const float s1i = s1[node];

  float ax = 0.f, ay = 0.f, az = 0.f, aw = 0.f;
  float wsum = 0.f;

  for (int c0 = 0; c0 < cnt; c0 += 64) {
    const int m = min(64, cnt - c0);
    int d = 0;
    float w = 0.f;
    if (lane < m) {
      d = edst[base + c0 + lane];
      const float logit = s1i + s2[d];
      const float lr = logit > 0.f ? logit : ALPHA * logit;
      w = __expf(-lr);
    }
#pragma unroll 4
    for (int e = 0; e < m; e += 4) {
      const int idx = e + g;              // <= 63 always
      const int dg = __shfl(d, idx);      // ds_bpermute
      const float wg = __shfl(w, idx);    // 0 for tail lanes
      const uint2 p = *(const uint2*)&hb[(size_t)dg * OUTD + seg * 4];
      ax = fmaf(wg, bflo(p.x), ax);
      ay = fmaf(wg, bfhi(p.x), ay);
      az = fmaf(wg, bflo(p.y), az);
      aw = fmaf(wg, bfhi(p.y), aw);
      wsum += wg;
    }
  }

  // reduce across the 4 edge-groups (seg preserved by xor 16/32)
#pragma unroll
  for (int off = 16; off <= 32; off <<= 1) {
    ax += __shfl_xor(ax, off);
    ay += __shfl_xor(ay, off);
    az += __shfl_xor(az, off);
    aw += __shfl_xor(aw, off);
    wsum += __shfl_xor(wsum, off);
  }

  if (g == 0) {
    const float inv = (cnt > 0) ? 1.f / wsum : 0.f;
    float4 r;
    float v;
    v = ax * inv; r.x = v > 0.f ? v : (__expf(v) - 1.f);
    v = ay * inv; r.y = v > 0.f ? v : (__expf(v) - 1.f);
    v = az * inv; r.z = v > 0.f ? v : (__expf(v) - 1.f);
    v = aw * inv; r.w = v > 0.f ? v : (__expf(v) - 1.f);
    *(float4*)&out[(size_t)node * OUTD + seg * 4] = r;
  }
}

// ---------------------------------------------------------------------------
extern "C" void kernel_launch(void* const* d_in, const int* in_sizes, int n_in,
                              void* d_out, int out_size, void* d_ws, size_t ws_size,
                              hipStream_t stream) {
  const float* x = (const float*)d_in[0];
  const int* ei = (const int*)d_in[1];
  const float* W = (const float*)d_in[2];
  const float* a = (const float*)d_in[3];
  float* out = (float*)d_out;

  // workspace layout (~22 MB)
  u16* hb = (u16*)d_ws;                   // NN*64 bf16 (6.4 MB)
  float* s1 = (float*)(hb + (size_t)NN * OUTD);  // NN
  float* s2 = s1 + NN;                    // NN
  int* rowstart = (int*)(s2 + NN);        // NN
  int* deg = rowstart + NN;               // NN
  int* bcnt = deg + NN;                   // P1*NB
  int* binoff = bcnt + TOT;               // P1*NB
  int* bsums = binoff + TOT;              // S1B
  int* bstart = bsums + S1B;              // NB+1
  u32* binned = (u32*)(bstart + NB + 1);  // NE
  int* edst = (int*)(binned + NE);        // NE

  const int* src = ei;
  const int* dst = ei + NE;

  hipLaunchKernelGGL(gemm_h_kernel, dim3(GEMM_BLOCKS), dim3(256), 0, stream,
                     x, W, a, hb, s1, s2);
  hipLaunchKernelGGL(hist_kernel, dim3(P1), dim3(256), 0, stream, src, bcnt);
  hipLaunchKernelGGL(scan1_kernel, dim3(S1B), dim3(256), 0, stream,
                     bcnt, binoff, bsums);
  hipLaunchKernelGGL(scan2_kernel, dim3(1), dim3(1024), 0, stream, bsums);
  hipLaunchKernelGGL(scan3_kernel, dim3(S1B), dim3(256), 0, stream,
                     binoff, bsums, bstart);
  hipLaunchKernelGGL(bin_kernel, dim3(P1), dim3(256), 0, stream,
                     src, dst, binoff, binned);
  hipLaunchKernelGGL(csr_kernel, dim3(NB), dim3(256), 0, stream,
                     binned, bstart, rowstart, deg, edst);
  hipLaunchKernelGGL(agg_kernel, dim3(NN / 4), dim3(256), 0, stream,
                     hb, s1, s2, rowstart, deg, edst, out);
}

// Round 9
// 205.248 us; speedup vs baseline: 1.7195x; 1.0258x over previous
//
#include <hip/hip_runtime.h>

#define NN 50000
#define NE 1600000
#define DIM 256
#define OUTD 64
#define ALPHA 0.2f

#define BSH 8                 // bucket = src >> 8 (256 nodes/bucket)
#define NB ((NN + 255) >> 8)  // 196 coarse buckets
#define P1 1000               // binning blocks
#define EPB (NE / P1)         // 1600 edges per block (exact, div by 4)
#define TOT (NB * P1)         // 196000 (p,b) pairs
#define S1B ((TOT + 255) / 256)  // 766 scan blocks

#define KC 64                 // gemm K-chunk (W staged in LDS)
#define MT 64                 // gemm rows per block
#define GEMM_BLOCKS ((NN + MT - 1) / MT)  // 782

typedef unsigned short u16;
typedef unsigned int u32;

__device__ __forceinline__ u16 f2bf(float f) {
  u32 b = __float_as_uint(f);
  b += 0x7FFFu + ((b >> 16) & 1u);  // RNE
  return (u16)(b >> 16);
}
__device__ __forceinline__ float bflo(u32 u) { return __uint_as_float(u << 16); }
__device__ __forceinline__ float bfhi(u32 u) { return __uint_as_float(u & 0xFFFF0000u); }

// ---------------------------------------------------------------------------
// h = x @ W (fp32 accum) -> packed bf16 hb; s1/s2 in epilogue.
// x is NOT staged in LDS: thread (tr,tc) reads its 4 rows directly from
// global as float4 — the 16 tc-lanes of a row share the address, so each
// wave-load touches only 4 unique lines (L1/L2-served, coalesced). LDS holds
// only W (4x ds_read_b128 per 4k per wave, 2-way bank alias = free). This
// removes the per-k ds_read_b32 x-reads that made the LDS pipe the wall.
// ---------------------------------------------------------------------------
__global__ __launch_bounds__(256) void gemm_h_kernel(
    const float* __restrict__ x, const float* __restrict__ W,
    const float* __restrict__ a, u16* __restrict__ hb,
    float* __restrict__ s1, float* __restrict__ s2)
{
  __shared__ float Wl[KC][OUTD];  // 16 KB
  const int t = threadIdx.x;
  const int tc = t & 15;
  const int tr = t >> 4;
  const int row0 = blockIdx.x * MT;
  const int r0 = row0 + tr * 4;

  const float4* xr[4];
#pragma unroll
  for (int j = 0; j < 4; ++j) {
    int r = r0 + j;
    if (r > NN - 1) r = NN - 1;  // tail clamp (loads only; stores guarded)
    xr[j] = (const float4*)(x + (size_t)r * DIM);
  }

  float acc[4][4] = {{0.f}};

  for (int kc = 0; kc < DIM; kc += KC) {
    {  // stage W chunk (KC*OUTD = 4096 contiguous floats)
      const float4* wsrc = (const float4*)(W + (size_t)kc * OUTD);
      float4* wdst = (float4*)&Wl[0][0];
#pragma unroll
      for (int i = 0; i < 4; ++i) wdst[t + 256 * i] = wsrc[t + 256 * i];
    }
    __syncthreads();

#pragma unroll 4
    for (int k4 = 0; k4 < KC / 4; ++k4) {
      float4 xq[4];
#pragma unroll
      for (int j = 0; j < 4; ++j) xq[j] = xr[j][(kc >> 2) + k4];
      float4 wq[4];
#pragma unroll
      for (int kk = 0; kk < 4; ++kk)
        wq[kk] = *(const float4*)&Wl[k4 * 4 + kk][tc * 4];
#pragma unroll
      for (int j = 0; j < 4; ++j) {
        acc[j][0] = fmaf(xq[j].x, wq[0].x, acc[j][0]);
        acc[j][1] = fmaf(xq[j].x, wq[0].y, acc[j][1]);
        acc[j][2] = fmaf(xq[j].x, wq[0].z, acc[j][2]);
        acc[j][3] = fmaf(xq[j].x, wq[0].w, acc[j][3]);
        acc[j][0] = fmaf(xq[j].y, wq[1].x, acc[j][0]);
        acc[j][1] = fmaf(xq[j].y, wq[1].y, acc[j][1]);
        acc[j][2] = fmaf(xq[j].y, wq[1].z, acc[j][2]);
        acc[j][3] = fmaf(xq[j].y, wq[1].w, acc[j][3]);
        acc[j][0] = fmaf(xq[j].z, wq[2].x, acc[j][0]);
        acc[j][1] = fmaf(xq[j].z, wq[2].y, acc[j][1]);
        acc[j][2] = fmaf(xq[j].z, wq[2].z, acc[j][2]);
        acc[j][3] = fmaf(xq[j].z, wq[2].w, acc[j][3]);
        acc[j][0] = fmaf(xq[j].w, wq[3].x, acc[j][0]);
        acc[j][1] = fmaf(xq[j].w, wq[3].y, acc[j][1]);
        acc[j][2] = fmaf(xq[j].w, wq[3].z, acc[j][2]);
        acc[j][3] = fmaf(xq[j].w, wq[3].w, acc[j][3]);
      }
    }
    __syncthreads();
  }

  const float a0 = a[tc * 4 + 0], a1 = a[tc * 4 + 1];
  const float a2 = a[tc * 4 + 2], a3 = a[tc * 4 + 3];
  const float b0 = a[OUTD + tc * 4 + 0], b1 = a[OUTD + tc * 4 + 1];
  const float b2 = a[OUTD + tc * 4 + 2], b3 = a[OUTD + tc * 4 + 3];

#pragma unroll
  for (int j = 0; j < 4; ++j) {
    const int r = r0 + j;
    float q1 = acc[j][0] * a0 + acc[j][1] * a1 + acc[j][2] * a2 + acc[j][3] * a3;
    float q2 = acc[j][0] * b0 + acc[j][1] * b1 + acc[j][2] * b2 + acc[j][3] * b3;
#pragma unroll
    for (int off = 8; off > 0; off >>= 1) {
      q1 += __shfl_xor(q1, off);
      q2 += __shfl_xor(q2, off);
    }
    if (r < NN) {
      uint2 p;
      p.x = (u32)f2bf(acc[j][0]) | ((u32)f2bf(acc[j][1]) << 16);
      p.y = (u32)f2bf(acc[j][2]) | ((u32)f2bf(acc[j][3]) << 16);
      *(uint2*)&hb[(size_t)r * OUTD + tc * 4] = p;
      if (tc == 0) { s1[r] = q1; s2[r] = q2; }
    }
  }
}

// ---------------------------------------------------------------------------
__global__ __launch_bounds__(256) void hist_kernel(const int* __restrict__ src,
                                                   int* __restrict__ bcnt) {
  __shared__ int lh[NB];
  const int t = threadIdx.x;
  for (int i = t; i < NB; i += 256) lh[i] = 0;
  __syncthreads();
  const int4* src4 = (const int4*)(src + blockIdx.x * EPB);
  for (int i = t; i < EPB / 4; i += 256) {
    const int4 s = src4[i];
    atomicAdd(&lh[s.x >> BSH], 1);
    atomicAdd(&lh[s.y >> BSH], 1);
    atomicAdd(&lh[s.z >> BSH], 1);
    atomicAdd(&lh[s.w >> BSH], 1);
  }
  __syncthreads();
  for (int i = t; i < NB; i += 256)
    bcnt[(size_t)blockIdx.x * NB + i] = lh[i];
}

// ---------------------------------------------------------------------------
__global__ __launch_bounds__(256) void scan1_kernel(const int* __restrict__ bcnt,
                                                    int* __restrict__ binoff,
                                                    int* __restrict__ bsums) {
  __shared__ int tmp[256];
  const int t = threadIdx.x;
  const int e = blockIdx.x * 256 + t;
  int v = 0;
  if (e < TOT) {
    const int b = e / P1;
    const int p = e - b * P1;
    v = bcnt[(size_t)p * NB + b];
  }
  int x = v;
  tmp[t] = v;
  __syncthreads();
  for (int off = 1; off < 256; off <<= 1) {
    const int y = (t >= off) ? tmp[t - off] : 0;
    __syncthreads();
    x += y;
    tmp[t] = x;
    __syncthreads();
  }
  if (e < TOT) binoff[e] = x - v;
  if (t == 255) bsums[blockIdx.x] = x;
}

__global__ __launch_bounds__(1024) void scan2_kernel(int* __restrict__ bsums) {
  __shared__ int tmp[1024];
  const int t = threadIdx.x;
  const int v = (t < S1B) ? bsums[t] : 0;
  int x = v;
  tmp[t] = v;
  __syncthreads();
  for (int off = 1; off < 1024; off <<= 1) {
    const int y = (t >= off) ? tmp[t - off] : 0;
    __syncthreads();
    x += y;
    tmp[t] = x;
    __syncthreads();
  }
  if (t < S1B) bsums[t] = x - v;
}

__global__ __launch_bounds__(256) void scan3_kernel(int* __restrict__ binoff,
                                                    const int* __restrict__ bsums,
                                                    int* __restrict__ bstart) {
  const int e = blockIdx.x * 256 + threadIdx.x;
  if (e < TOT) {
    const int val = binoff[e] + bsums[blockIdx.x];
    binoff[e] = val;
    const int b = e / P1;
    if (e == b * P1) bstart[b] = val;  // p == 0
  }
  if (e == 0) bstart[NB] = NE;
}

// ---------------------------------------------------------------------------
__global__ __launch_bounds__(256) void bin_kernel(const int* __restrict__ src,
                                                  const int* __restrict__ dst,
                                                  const int* __restrict__ binoff,
                                                  u32* __restrict__ binned) {
  __shared__ int lcur[NB];
  const int t = threadIdx.x;
  for (int b = t; b < NB; b += 256)
    lcur[b] = binoff[(size_t)b * P1 + blockIdx.x];
  __syncthreads();
  const int4* src4 = (const int4*)(src + blockIdx.x * EPB);
  const int4* dst4 = (const int4*)(dst + blockIdx.x * EPB);
  for (int i = t; i < EPB / 4; i += 256) {
    const int4 s = src4[i];
    const int4 d = dst4[i];
    int pos;
    pos = atomicAdd(&lcur[s.x >> BSH], 1);
    binned[pos] = ((u32)(s.x & 255) << 16) | (u32)d.x;
    pos = atomicAdd(&lcur[s.y >> BSH], 1);
    binned[pos] = ((u32)(s.y & 255) << 16) | (u32)d.y;
    pos = atomicAdd(&lcur[s.z >> BSH], 1);
    binned[pos] = ((u32)(s.z & 255) << 16) | (u32)d.z;
    pos = atomicAdd(&lcur[s.w >> BSH], 1);
    binned[pos] = ((u32)(s.w & 255) << 16) | (u32)d.w;
  }
}

// ---------------------------------------------------------------------------
__global__ __launch_bounds__(256) void csr_kernel(const u32* __restrict__ binned,
                                                  const int* __restrict__ bstart,
                                                  int* __restrict__ rowstart,
                                                  int* __restrict__ deg,
                                                  int* __restrict__ edst) {
  __shared__ int cnt[256];
  __shared__ int off[256];
  const int b = blockIdx.x;
  const int beg = bstart[b], end = bstart[b + 1];
  const int t = threadIdx.x;
  cnt[t] = 0;
  __syncthreads();
  for (int i = beg + t; i < end; i += 256)
    atomicAdd(&cnt[binned[i] >> 16], 1);
  __syncthreads();
  const int v = cnt[t];
  int x = v;
  off[t] = v;
  __syncthreads();
  for (int o = 1; o < 256; o <<= 1) {
    const int y = (t >= o) ? off[t - o] : 0;
    __syncthreads();
    x += y;
    off[t] = x;
    __syncthreads();
  }
  off[t] = beg + x - v;
  const int node = (b << BSH) + t;
  if (node < NN) { rowstart[node] = beg + x - v; deg[node] = v; }
  __syncthreads();
  for (int i = beg + t; i < end; i += 256) {
    const u32 p = binned[i];
    const int slot = atomicAdd(&off[p >> 16], 1);
    edst[slot] = (int)(p & 0xFFFFu);
  }
}

// ---------------------------------------------------------------------------
// Aggregation: one wave per node; 8 edges per inner iteration.
// lane = (g = lane>>3 edge-group, seg = lane&7). Group g handles edge c+e+g;
// each lane loads uint4 = 8 bf16 dims -> one gather instr covers 8 rows.
// (d,w) broadcast via ds_bpermute; tail lanes contribute w=0. Epilogue:
// xor 8/16/32 cross-group reduce; g==0 lanes store 2x float4.
// ---------------------------------------------------------------------------
__global__ __launch_bounds__(256) void agg_kernel(
    const u16* __restrict__ hb, const float* __restrict__ s1,
    const float* __restrict__ s2, const int* __restrict__ pre,
    const int* __restrict__ deg, const int* __restrict__ edst,
    float* __restrict__ out)
{
  const int lane = threadIdx.x & 63;
  const int g = lane >> 3;
  const int seg = lane & 7;
  const int node =
      __builtin_amdgcn_readfirstlane(blockIdx.x * 4 + (threadIdx.x >> 6));
  const int base = pre[node];
  const int cnt = deg[node];
  const float s1i = s1[node];

  float a0 = 0.f, a1 = 0.f, a2 = 0.f, a3 = 0.f;
  float a4 = 0.f, a5 = 0.f, a6 = 0.f, a7 = 0.f;
  float wsum = 0.f;

  for (int c0 = 0; c0 < cnt; c0 += 64) {
    const int m = min(64, cnt - c0);
    int d = 0;
    float w = 0.f;
    if (lane < m) {
      d = edst[base + c0 + lane];
      const float logit = s1i + s2[d];
      const float lr = logit > 0.f ? logit : ALPHA * logit;
      w = __expf(-lr);
    }
#pragma unroll 4
    for (int e = 0; e < m; e += 8) {
      const int idx = e + g;              // <= 63 always
      const int dg = __shfl(d, idx);      // ds_bpermute
      const float wg = __shfl(w, idx);    // 0 for tail lanes
      const uint4 p = *(const uint4*)&hb[(size_t)dg * OUTD + seg * 8];
      a0 = fmaf(wg, bflo(p.x), a0);
      a1 = fmaf(wg, bfhi(p.x), a1);
      a2 = fmaf(wg, bflo(p.y), a2);
      a3 = fmaf(wg, bfhi(p.y), a3);
      a4 = fmaf(wg, bflo(p.z), a4);
      a5 = fmaf(wg, bfhi(p.z), a5);
      a6 = fmaf(wg, bflo(p.w), a6);
      a7 = fmaf(wg, bfhi(p.w), a7);
      wsum += wg;
    }
  }

#pragma unroll
  for (int off = 8; off <= 32; off <<= 1) {
    a0 += __shfl_xor(a0, off);
    a1 += __shfl_xor(a1, off);
    a2 += __shfl_xor(a2, off);
    a3 += __shfl_xor(a3, off);
    a4 += __shfl_xor(a4, off);
    a5 += __shfl_xor(a5, off);
    a6 += __shfl_xor(a6, off);
    a7 += __shfl_xor(a7, off);
    wsum += __shfl_xor(wsum, off);
  }

  if (g == 0) {
    const float inv = (cnt > 0) ? 1.f / wsum : 0.f;
    float4 r;
    float v;
    v = a0 * inv; r.x = v > 0.f ? v : (__expf(v) - 1.f);
    v = a1 * inv; r.y = v > 0.f ? v : (__expf(v) - 1.f);
    v = a2 * inv; r.z = v > 0.f ? v : (__expf(v) - 1.f);
    v = a3 * inv; r.w = v > 0.f ? v : (__expf(v) - 1.f);
    *(float4*)&out[(size_t)node * OUTD + seg * 8] = r;
    v = a4 * inv; r.x = v > 0.f ? v : (__expf(v) - 1.f);
    v = a5 * inv; r.y = v > 0.f ? v : (__expf(v) - 1.f);
    v = a6 * inv; r.z = v > 0.f ? v : (__expf(v) - 1.f);
    v = a7 * inv; r.w = v > 0.f ? v : (__expf(v) - 1.f);
    *(float4*)&out[(size_t)node * OUTD + seg * 8 + 4] = r;
  }
}

// ---------------------------------------------------------------------------
extern "C" void kernel_launch(void* const* d_in, const int* in_sizes, int n_in,
                              void* d_out, int out_size, void* d_ws, size_t ws_size,
                              hipStream_t stream) {
  const float* x = (const float*)d_in[0];
  const int* ei = (const int*)d_in[1];
  const float* W = (const float*)d_in[2];
  const float* a = (const float*)d_in[3];
  float* out = (float*)d_out;

  // workspace layout (~22 MB)
  u16* hb = (u16*)d_ws;                   // NN*64 bf16 (6.4 MB)
  float* s1 = (float*)(hb + (size_t)NN * OUTD);  // NN
  float* s2 = s1 + NN;                    // NN
  int* rowstart = (int*)(s2 + NN);        // NN
  int* deg = rowstart + NN;               // NN
  int* bcnt = deg + NN;                   // P1*NB
  int* binoff = bcnt + TOT;               // P1*NB
  int* bsums = binoff + TOT;              // S1B
  int* bstart = bsums + S1B;              // NB+1
  u32* binned = (u32*)(bstart + NB + 1);  // NE
  int* edst = (int*)(binned + NE);        // NE

  const int* src = ei;
  const int* dst = ei + NE;

  hipLaunchKernelGGL(gemm_h_kernel, dim3(GEMM_BLOCKS), dim3(256), 0, stream,
                     x, W, a, hb, s1, s2);
  hipLaunchKernelGGL(hist_kernel, dim3(P1), dim3(256), 0, stream, src, bcnt);
  hipLaunchKernelGGL(scan1_kernel, dim3(S1B), dim3(256), 0, stream,
                     bcnt, binoff, bsums);
  hipLaunchKernelGGL(scan2_kernel, dim3(1), dim3(1024), 0, stream, bsums);
  hipLaunchKernelGGL(scan3_kernel, dim3(S1B), dim3(256), 0, stream,
                     binoff, bsums, bstart);
  hipLaunchKernelGGL(bin_kernel, dim3(P1), dim3(256), 0, stream,
                     src, dst, binoff, binned);
  hipLaunchKernelGGL(csr_kernel, dim3(NB), dim3(256), 0, stream,
                     binned, bstart, rowstart, deg, edst);
  hipLaunchKernelGGL(agg_kernel, dim3(NN / 4), dim3(256), 0, stream,
                     hb, s1, s2, rowstart, deg, edst, out);
}

// Round 10
// 183.362 us; speedup vs baseline: 1.9247x; 1.1194x over previous
//
#include <hip/hip_runtime.h>

#define NN 50000
#define NE 1600000
#define DIM 256
#define OUTD 64
#define ALPHA 0.2f

#define BSH 8                 // bucket = src >> 8 (256 nodes/bucket)
#define NB ((NN + 255) >> 8)  // 196 coarse buckets
#define P1 1000               // binning blocks
#define EPB (NE / P1)         // 1600 edges per block (exact, div by 4)
#define TOT (NB * P1)         // 196000 (p,b) pairs
#define S1B ((TOT + 255) / 256)  // 766 scan blocks

#define GEMM_BLOCKS ((NN + 63) / 64)  // 782 (64 rows/block = 16 rows x 4 waves)
#define WSTRIDE 264           // Wt LDS row stride in bf16 (256 + 8 pad; b128 reads 2-way alias = free)

typedef unsigned short u16;
typedef unsigned int u32;
typedef __attribute__((ext_vector_type(8))) short short8;   // 8 bf16 MFMA frag
typedef __attribute__((ext_vector_type(4))) float floatx4;  // MFMA accum

__device__ __forceinline__ u16 f2bf(float f) {
  u32 b = __float_as_uint(f);
  b += 0x7FFFu + ((b >> 16) & 1u);  // RNE
  return (u16)(b >> 16);
}
__device__ __forceinline__ float bflo(u32 u) { return __uint_as_float(u << 16); }
__device__ __forceinline__ float bfhi(u32 u) { return __uint_as_float(u & 0xFFFF0000u); }

// ---------------------------------------------------------------------------
// One-time W transpose+cast: wt[n][k] bf16 pairs packed in u32 (wt[n*128+kp]
// holds k=2kp (lo) and k=2kp+1 (hi)). 8192 threads.
// ---------------------------------------------------------------------------
__global__ __launch_bounds__(256) void wt_kernel(const float* __restrict__ W,
                                                 u32* __restrict__ wt) {
  const int g = blockIdx.x * 256 + threadIdx.x;  // 0..8191
  const int n = g >> 7;
  const int kp = g & 127;
  const float lo = W[(size_t)(2 * kp) * OUTD + n];
  const float hi = W[(size_t)(2 * kp + 1) * OUTD + n];
  wt[g] = (u32)f2bf(lo) | ((u32)f2bf(hi) << 16);
}

// ---------------------------------------------------------------------------
// h = x @ W via bf16 MFMA (fp32 accum), stored packed bf16; s1/s2 in epilogue.
// Block = 4 waves x 16 rows = 64 rows. Per wave per 32-K step: 2 coalesced
// float4 x-loads -> pack A-frag (A[m=lane&15][k=quad*8+j]); 4x ds_read_b128
// B-frags from LDS W^T; 4x mfma_f32_16x16x32_bf16 (one per 16-col tile).
// C/D layout: col = lane&15, row = quad*4 + reg. Compute moves to the matrix
// pipe; kernel becomes memory-bound on the 51 MB x read.
// ---------------------------------------------------------------------------
__global__ __launch_bounds__(256) void gemm_h_kernel(
    const float* __restrict__ x, const u32* __restrict__ wt,
    const float* __restrict__ a, u16* __restrict__ hb,
    float* __restrict__ s1, float* __restrict__ s2)
{
  __shared__ u16 Wl[OUTD * WSTRIDE];  // 33 KB
  const int t = threadIdx.x;
  {  // stage W^T: 2048 uint4 chunks, coalesced global read, padded LDS write
    const uint4* srcv = (const uint4*)wt;
#pragma unroll
    for (int i = 0; i < 8; ++i) {
      const int c = t + 256 * i;
      const int n = c >> 5;   // 32 x 16B chunks per 256-k row
      const int k8 = c & 31;
      *(uint4*)&Wl[n * WSTRIDE + k8 * 8] = srcv[c];
    }
  }
  __syncthreads();

  const int lane = t & 63;
  const int wv = t >> 6;
  const int n = lane & 15;
  const int quad = lane >> 4;
  int rb = blockIdx.x * 64 + wv * 16;
  if (rb > NN - 16) rb = NN - 16;  // tail clamp (duplicate waves store identical)
  const int row = rb + n;
  const float4* xrow = (const float4*)(x + (size_t)row * DIM);

  floatx4 acc[4] = {{0.f, 0.f, 0.f, 0.f},
                    {0.f, 0.f, 0.f, 0.f},
                    {0.f, 0.f, 0.f, 0.f},
                    {0.f, 0.f, 0.f, 0.f}};

#pragma unroll
  for (int kk = 0; kk < 8; ++kk) {
    const float4 lo = xrow[kk * 8 + quad * 2];
    const float4 hi = xrow[kk * 8 + quad * 2 + 1];
    union { u32 u[4]; short8 s; } af;
    af.u[0] = (u32)f2bf(lo.x) | ((u32)f2bf(lo.y) << 16);
    af.u[1] = (u32)f2bf(lo.z) | ((u32)f2bf(lo.w) << 16);
    af.u[2] = (u32)f2bf(hi.x) | ((u32)f2bf(hi.y) << 16);
    af.u[3] = (u32)f2bf(hi.z) | ((u32)f2bf(hi.w) << 16);
#pragma unroll
    for (int nt = 0; nt < 4; ++nt) {
      const short8 bf =
          *(const short8*)&Wl[(nt * 16 + n) * WSTRIDE + kk * 32 + quad * 8];
      acc[nt] = __builtin_amdgcn_mfma_f32_16x16x32_bf16(af.s, bf, acc[nt], 0, 0, 0);
    }
  }

  float av1[4], av2[4];
#pragma unroll
  for (int nt = 0; nt < 4; ++nt) {
    av1[nt] = a[nt * 16 + n];
    av2[nt] = a[OUTD + nt * 16 + n];
  }

#pragma unroll
  for (int reg = 0; reg < 4; ++reg) {
    const int r = rb + quad * 4 + reg;
    float q1 = acc[0][reg] * av1[0] + acc[1][reg] * av1[1] +
               acc[2][reg] * av1[2] + acc[3][reg] * av1[3];
    float q2 = acc[0][reg] * av2[0] + acc[1][reg] * av2[1] +
               acc[2][reg] * av2[2] + acc[3][reg] * av2[3];
#pragma unroll
    for (int off = 1; off <= 8; off <<= 1) {
      q1 += __shfl_xor(q1, off);
      q2 += __shfl_xor(q2, off);
    }
    if (n == 0) { s1[r] = q1; s2[r] = q2; }
#pragma unroll
    for (int nt = 0; nt < 4; ++nt)
      hb[(size_t)r * OUTD + nt * 16 + n] = f2bf(acc[nt][reg]);
  }
}

// ---------------------------------------------------------------------------
__global__ __launch_bounds__(256) void hist_kernel(const int* __restrict__ src,
                                                   int* __restrict__ bcnt) {
  __shared__ int lh[NB];
  const int t = threadIdx.x;
  for (int i = t; i < NB; i += 256) lh[i] = 0;
  __syncthreads();
  const int4* src4 = (const int4*)(src + blockIdx.x * EPB);
  for (int i = t; i < EPB / 4; i += 256) {
    const int4 s = src4[i];
    atomicAdd(&lh[s.x >> BSH], 1);
    atomicAdd(&lh[s.y >> BSH], 1);
    atomicAdd(&lh[s.z >> BSH], 1);
    atomicAdd(&lh[s.w >> BSH], 1);
  }
  __syncthreads();
  for (int i = t; i < NB; i += 256)
    bcnt[(size_t)blockIdx.x * NB + i] = lh[i];
}

// ---------------------------------------------------------------------------
__global__ __launch_bounds__(256) void scan1_kernel(const int* __restrict__ bcnt,
                                                    int* __restrict__ binoff,
                                                    int* __restrict__ bsums) {
  __shared__ int tmp[256];
  const int t = threadIdx.x;
  const int e = blockIdx.x * 256 + t;
  int v = 0;
  if (e < TOT) {
    const int b = e / P1;
    const int p = e - b * P1;
    v = bcnt[(size_t)p * NB + b];
  }
  int x = v;
  tmp[t] = v;
  __syncthreads();
  for (int off = 1; off < 256; off <<= 1) {
    const int y = (t >= off) ? tmp[t - off] : 0;
    __syncthreads();
    x += y;
    tmp[t] = x;
    __syncthreads();
  }
  if (e < TOT) binoff[e] = x - v;
  if (t == 255) bsums[blockIdx.x] = x;
}

__global__ __launch_bounds__(1024) void scan2_kernel(int* __restrict__ bsums) {
  __shared__ int tmp[1024];
  const int t = threadIdx.x;
  const int v = (t < S1B) ? bsums[t] : 0;
  int x = v;
  tmp[t] = v;
  __syncthreads();
  for (int off = 1; off < 1024; off <<= 1) {
    const int y = (t >= off) ? tmp[t - off] : 0;
    __syncthreads();
    x += y;
    tmp[t] = x;
    __syncthreads();
  }
  if (t < S1B) bsums[t] = x - v;
}

__global__ __launch_bounds__(256) void scan3_kernel(int* __restrict__ binoff,
                                                    const int* __restrict__ bsums,
                                                    int* __restrict__ bstart) {
  const int e = blockIdx.x * 256 + threadIdx.x;
  if (e < TOT) {
    const int val = binoff[e] + bsums[blockIdx.x];
    binoff[e] = val;
    const int b = e / P1;
    if (e == b * P1) bstart[b] = val;  // p == 0
  }
  if (e == 0) bstart[NB] = NE;
}

// ---------------------------------------------------------------------------
__global__ __launch_bounds__(256) void bin_kernel(const int* __restrict__ src,
                                                  const int* __restrict__ dst,
                                                  const int* __restrict__ binoff,
                                                  u32* __restrict__ binned) {
  __shared__ int lcur[NB];
  const int t = threadIdx.x;
  for (int b = t; b < NB; b += 256)
    lcur[b] = binoff[(size_t)b * P1 + blockIdx.x];
  __syncthreads();
  const int4* src4 = (const int4*)(src + blockIdx.x * EPB);
  const int4* dst4 = (const int4*)(dst + blockIdx.x * EPB);
  for (int i = t; i < EPB / 4; i += 256) {
    const int4 s = src4[i];
    const int4 d = dst4[i];
    int pos;
    pos = atomicAdd(&lcur[s.x >> BSH], 1);
    binned[pos] = ((u32)(s.x & 255) << 16) | (u32)d.x;
    pos = atomicAdd(&lcur[s.y >> BSH], 1);
    binned[pos] = ((u32)(s.y & 255) << 16) | (u32)d.y;
    pos = atomicAdd(&lcur[s.z >> BSH], 1);
    binned[pos] = ((u32)(s.z & 255) << 16) | (u32)d.z;
    pos = atomicAdd(&lcur[s.w >> BSH], 1);
    binned[pos] = ((u32)(s.w & 255) << 16) | (u32)d.w;
  }
}

// ---------------------------------------------------------------------------
__global__ __launch_bounds__(256) void csr_kernel(const u32* __restrict__ binned,
                                                  const int* __restrict__ bstart,
                                                  int* __restrict__ rowstart,
                                                  int* __restrict__ deg,
                                                  int* __restrict__ edst) {
  __shared__ int cnt[256];
  __shared__ int off[256];
  const int b = blockIdx.x;
  const int beg = bstart[b], end = bstart[b + 1];
  const int t = threadIdx.x;
  cnt[t] = 0;
  __syncthreads();
  for (int i = beg + t; i < end; i += 256)
    atomicAdd(&cnt[binned[i] >> 16], 1);
  __syncthreads();
  const int v = cnt[t];
  int x = v;
  off[t] = v;
  __syncthreads();
  for (int o = 1; o < 256; o <<= 1) {
    const int y = (t >= o) ? off[t - o] : 0;
    __syncthreads();
    x += y;
    off[t] = x;
    __syncthreads();
  }
  off[t] = beg + x - v;
  const int node = (b << BSH) + t;
  if (node < NN) { rowstart[node] = beg + x - v; deg[node] = v; }
  __syncthreads();
  for (int i = beg + t; i < end; i += 256) {
    const u32 p = binned[i];
    const int slot = atomicAdd(&off[p >> 16], 1);
    edst[slot] = (int)(p & 0xFFFFu);
  }
}

// ---------------------------------------------------------------------------
// Aggregation: one wave per node; 8 edges per inner iteration (unchanged).
// ---------------------------------------------------------------------------
__global__ __launch_bounds__(256) void agg_kernel(
    const u16* __restrict__ hb, const float* __restrict__ s1,
    const float* __restrict__ s2, const int* __restrict__ pre,
    const int* __restrict__ deg, const int* __restrict__ edst,
    float* __restrict__ out)
{
  const int lane = threadIdx.x & 63;
  const int g = lane >> 3;
  const int seg = lane & 7;
  const int node =
      __builtin_amdgcn_readfirstlane(blockIdx.x * 4 + (threadIdx.x >> 6));
  const int base = pre[node];
  const int cnt = deg[node];
  const float s1i = s1[node];

  float a0 = 0.f, a1 = 0.f, a2 = 0.f, a3 = 0.f;
  float a4 = 0.f, a5 = 0.f, a6 = 0.f, a7 = 0.f;
  float wsum = 0.f;

  for (int c0 = 0; c0 < cnt; c0 += 64) {
    const int m = min(64, cnt - c0);
    int d = 0;
    float w = 0.f;
    if (lane < m) {
      d = edst[base + c0 + lane];
      const float logit = s1i + s2[d];
      const float lr = logit > 0.f ? logit : ALPHA * logit;
      w = __expf(-lr);
    }
#pragma unroll 4
    for (int e = 0; e < m; e += 8) {
      const int idx = e + g;
      const int dg = __shfl(d, idx);
      const float wg = __shfl(w, idx);
      const uint4 p = *(const uint4*)&hb[(size_t)dg * OUTD + seg * 8];
      a0 = fmaf(wg, bflo(p.x), a0);
      a1 = fmaf(wg, bfhi(p.x), a1);
      a2 = fmaf(wg, bflo(p.y), a2);
      a3 = fmaf(wg, bfhi(p.y), a3);
      a4 = fmaf(wg, bflo(p.z), a4);
      a5 = fmaf(wg, bfhi(p.z), a5);
      a6 = fmaf(wg, bflo(p.w), a6);
      a7 = fmaf(wg, bfhi(p.w), a7);
      wsum += wg;
    }
  }

#pragma unroll
  for (int off = 8; off <= 32; off <<= 1) {
    a0 += __shfl_xor(a0, off);
    a1 += __shfl_xor(a1, off);
    a2 += __shfl_xor(a2, off);
    a3 += __shfl_xor(a3, off);
    a4 += __shfl_xor(a4, off);
    a5 += __shfl_xor(a5, off);
    a6 += __shfl_xor(a6, off);
    a7 += __shfl_xor(a7, off);
    wsum += __shfl_xor(wsum, off);
  }

  if (g == 0) {
    const float inv = (cnt > 0) ? 1.f / wsum : 0.f;
    float4 r;
    float v;
    v = a0 * inv; r.x = v > 0.f ? v : (__expf(v) - 1.f);
    v = a1 * inv; r.y = v > 0.f ? v : (__expf(v) - 1.f);
    v = a2 * inv; r.z = v > 0.f ? v : (__expf(v) - 1.f);
    v = a3 * inv; r.w = v > 0.f ? v : (__expf(v) - 1.f);
    *(float4*)&out[(size_t)node * OUTD + seg * 8] = r;
    v = a4 * inv; r.x = v > 0.f ? v : (__expf(v) - 1.f);
    v = a5 * inv; r.y = v > 0.f ? v : (__expf(v) - 1.f);
    v = a6 * inv; r.z = v > 0.f ? v : (__expf(v) - 1.f);
    v = a7 * inv; r.w = v > 0.f ? v : (__expf(v) - 1.f);
    *(float4*)&out[(size_t)node * OUTD + seg * 8 + 4] = r;
  }
}

// ---------------------------------------------------------------------------
extern "C" void kernel_launch(void* const* d_in, const int* in_sizes, int n_in,
                              void* d_out, int out_size, void* d_ws, size_t ws_size,
                              hipStream_t stream) {
  const float* x = (const float*)d_in[0];
  const int* ei = (const int*)d_in[1];
  const float* W = (const float*)d_in[2];
  const float* a = (const float*)d_in[3];
  float* out = (float*)d_out;

  // workspace layout (~22 MB)
  u16* hb = (u16*)d_ws;                   // NN*64 bf16 (6.4 MB)
  float* s1 = (float*)(hb + (size_t)NN * OUTD);  // NN
  float* s2 = s1 + NN;                    // NN
  int* rowstart = (int*)(s2 + NN);        // NN
  int* deg = rowstart + NN;               // NN
  int* bcnt = deg + NN;                   // P1*NB
  int* binoff = bcnt + TOT;               // P1*NB
  int* bsums = binoff + TOT;              // S1B
  int* bstart = bsums + S1B;              // NB+1
  u32* binned = (u32*)(bstart + NB + 1);  // NE
  int* edst = (int*)(binned + NE);        // NE
  u32* wt = (u32*)(edst + NE);            // 8192 (32 KB W^T bf16)

  const int* src = ei;
  const int* dst = ei + NE;

  hipLaunchKernelGGL(wt_kernel, dim3(32), dim3(256), 0, stream, W, wt);
  hipLaunchKernelGGL(gemm_h_kernel, dim3(GEMM_BLOCKS), dim3(256), 0, stream,
                     x, wt, a, hb, s1, s2);
  hipLaunchKernelGGL(hist_kernel, dim3(P1), dim3(256), 0, stream, src, bcnt);
  hipLaunchKernelGGL(scan1_kernel, dim3(S1B), dim3(256), 0, stream,
                     bcnt, binoff, bsums);
  hipLaunchKernelGGL(scan2_kernel, dim3(1), dim3(1024), 0, stream, bsums);
  hipLaunchKernelGGL(scan3_kernel, dim3(S1B), dim3(256), 0, stream,
                     binoff, bsums, bstart);
  hipLaunchKernelGGL(bin_kernel, dim3(P1), dim3(256), 0, stream,
                     src, dst, binoff, binned);
  hipLaunchKernelGGL(csr_kernel, dim3(NB), dim3(256), 0, stream,
                     binned, bstart, rowstart, deg, edst);
  hipLaunchKernelGGL(agg_kernel, dim3(NN / 4), dim3(256), 0, stream,
                     hb, s1, s2, rowstart, deg, edst, out);
}